// Round 14
// baseline (96.839 us; speedup 1.0000x reference)
//
#include <hip/hip_runtime.h>
#include <hip/hip_bf16.h>

#define T_STEPS 100
#define D_IN    65536
#define HID     256
#define HTOT    512
#define BETA    0.95f
#define THRESH  1.0f

typedef __bf16 bf16x8 __attribute__((ext_vector_type(8)));
typedef float  f32x16 __attribute__((ext_vector_type(16)));

__device__ __forceinline__ void gload_lds16(const void* g, void* l) {
    __builtin_amdgcn_global_load_lds(
        (const __attribute__((address_space(1))) void*)g,
        (__attribute__((address_space(3))) void*)l, 16, 0, 0);
}

// ---- GEMM1 (R13 + low-transaction W staging).
// x: [2][128 rows][32k] fp32 double-buffer (16 KB each), 8-granule XOR swizzle,
//    4 gload_lds/thread/step, fully coalesced (1 tx per wave-instr).
// W: [128 rows][64k] fp32 SINGLE buffer (32 KB), 256-B contiguous per row
//    (4 rows per wave-instr -> 4 tx vs 8 before), 16-granule XOR swizzle,
//    rewritten every 2 steps (gets a full step of flight; step >> 900 cyc).
// vmcnt(4) every step; W issued BEFORE x at odd steps so oldest-4 = exact.
// 64 KB LDS -> 2 blocks/CU. 3-product bf16 hi/mid MFMA, order == R13.
// Block = 256 thr = 4 waves, wave owns 64t x 64h quadrant. XCD swizzle == R11.
__global__ __launch_bounds__(256, 2) void k_gemm1(
    const float* __restrict__ aW1,   // [256][65536]
    const float* __restrict__ cW1,   // [256][65536]
    const float* __restrict__ x,     // [100][65536]
    float* __restrict__ P,           // [NS][100][512]
    int nsteps)                      // 32-k steps per split (16 at NS=128)
{
    // bijective swizzle: d -> xcd = d%8, slot = d/8, s = xcd*16+(slot&15), ht = slot>>4
    const int d    = blockIdx.x;
    const int xcd  = d & 7;
    const int sl   = d >> 3;
    const int s    = xcd * 16 + (sl & 15);
    const int ht   = sl >> 4;

    const int tid  = threadIdx.x;
    const int lane = tid & 63;
    const int l31  = lane & 31;
    const int h5   = lane >> 5;
    const int wv   = tid >> 6;           // 0..3
    const int wt   = (wv & 1) * 64;      // wave t-offset
    const int wh   = (wv >> 1) * 64;     // wave h-offset (64-wide quadrant)

    __shared__ __align__(16) char smem[65536];   // [0,32K) x dbuf, [32K,64K) W

    const float* Wbase = (ht < 2) ? (aW1 + (size_t)ht * 128 * D_IN)
                                  : (cW1 + (size_t)(ht - 2) * 128 * D_IN);

    // x staging: 1024 granules (row = idx>>3, g = idx&7), source col swizzled
    const float* xsrc[4];
#pragma unroll
    for (int o = 0; o < 4; o++) {
        const int idx = o * 256 + tid;
        const int row = idx >> 3, g = idx & 7;
        const int xrow = (row < T_STEPS) ? row : (T_STEPS - 1);  // pad rows: garbage, discarded
        xsrc[o] = x + (size_t)xrow * D_IN + (g ^ (row & 7)) * 4;
    }
    // W staging: 2048 granules (row = idx>>4, g = idx&15), 256-B rows, swizzled
    const float* wsrc[8];
#pragma unroll
    for (int o = 0; o < 8; o++) {
        const int idx = o * 256 + tid;
        const int row = idx >> 4, g = idx & 15;
        wsrc[o] = Wbase + (size_t)row * D_IN + ((g ^ (row & 15)) * 4);
    }
    const int gk0 = s * nsteps;            // 32-k block base
    const int gw0 = s * (nsteps >> 1);     // 64-k window base

    f32x16 acc00, acc01, acc10, acc11;
#pragma unroll
    for (int i = 0; i < 16; i++) {
        acc00[i] = 0.f; acc01[i] = 0.f; acc10[i] = 0.f; acc11[i] = 0.f;
    }

#define XSTAGE(i) do {                                                        \
    char* b_ = smem + ((i) & 1) * 16384;                                      \
    const int kc_ = (gk0 + (i)) * 32;                                         \
    _Pragma("unroll")                                                         \
    for (int o = 0; o < 4; o++) {                                             \
        const int g_ = o * 256 + tid;                                         \
        gload_lds16(xsrc[o] + kc_, b_ + g_ * 16);                             \
    }                                                                         \
} while (0)

#define WSTAGE(w) do {                                                        \
    const int kc_ = (gw0 + (w)) * 64;                                         \
    _Pragma("unroll")                                                         \
    for (int o = 0; o < 8; o++) {                                             \
        const int g_ = o * 256 + tid;                                         \
        gload_lds16(wsrc[o] + kc_, smem + 32768 + g_ * 16);                   \
    }                                                                         \
} while (0)

#define CVT8(dsth, dstm, va, vb) do {                                         \
    float f_[8] = {va.x, va.y, va.z, va.w, vb.x, vb.y, vb.z, vb.w};           \
    _Pragma("unroll")                                                         \
    for (int e = 0; e < 8; e++) {                                             \
        __bf16 h = (__bf16)f_[e];                                             \
        dsth[e] = h; dstm[e] = (__bf16)(f_[e] - (float)h);                    \
    }                                                                         \
} while (0)

#define COMPUTE(i) do {                                                       \
    const char* b_ = smem + ((i) & 1) * 16384;                                \
    const char* wb_ = smem + 32768;                                           \
    const int khalf_ = (i) & 1;                                               \
    _Pragma("unroll")                                                         \
    for (int s16 = 0; s16 < 2; s16++) {                                       \
        const int gba = s16 * 4 + h5 * 2;          /* A granule base (8-g) */ \
        const int gbw = khalf_ * 8 + gba;          /* W granule base (16-g) */\
        /* A fragments: x fp32 rows r0, r1 */                                 \
        const int r0 = wt + l31, r1 = r0 + 32;                                \
        const char* xr0_ = b_ + r0 * 128;                                     \
        const char* xr1_ = b_ + r1 * 128;                                     \
        float4 xa0 = *(const float4*)(xr0_ + ((gba ^ (r0 & 7)) * 16));        \
        float4 xb0 = *(const float4*)(xr0_ + (((gba + 1) ^ (r0 & 7)) * 16));  \
        float4 xa1 = *(const float4*)(xr1_ + ((gba ^ (r1 & 7)) * 16));        \
        float4 xb1 = *(const float4*)(xr1_ + (((gba + 1) ^ (r1 & 7)) * 16));  \
        bf16x8 a0h, a0m, a1h, a1m;                                            \
        CVT8(a0h, a0m, xa0, xb0);                                             \
        CVT8(a1h, a1m, xa1, xb1);                                             \
        /* W fragments: rows hrA, hrB from the 256-B-row W buffer */          \
        const int hrA = wh + l31, hrB = hrA + 32;                             \
        const char* wrA_ = wb_ + hrA * 256;                                   \
        const char* wrB_ = wb_ + hrB * 256;                                   \
        float4 waA = *(const float4*)(wrA_ + ((gbw ^ (hrA & 15)) * 16));      \
        float4 wbA = *(const float4*)(wrA_ + (((gbw + 1) ^ (hrA & 15)) * 16));\
        float4 waB = *(const float4*)(wrB_ + ((gbw ^ (hrB & 15)) * 16));      \
        float4 wbB = *(const float4*)(wrB_ + (((gbw + 1) ^ (hrB & 15)) * 16));\
        bf16x8 bhA, bmA, bhB, bmB;                                            \
        CVT8(bhA, bmA, waA, wbA);                                             \
        CVT8(bhB, bmB, waB, wbB);                                             \
        acc00 = __builtin_amdgcn_mfma_f32_32x32x16_bf16(a0m, bhA, acc00, 0,0,0); \
        acc00 = __builtin_amdgcn_mfma_f32_32x32x16_bf16(a0h, bmA, acc00, 0,0,0); \
        acc00 = __builtin_amdgcn_mfma_f32_32x32x16_bf16(a0h, bhA, acc00, 0,0,0); \
        acc01 = __builtin_amdgcn_mfma_f32_32x32x16_bf16(a0m, bhB, acc01, 0,0,0); \
        acc01 = __builtin_amdgcn_mfma_f32_32x32x16_bf16(a0h, bmB, acc01, 0,0,0); \
        acc01 = __builtin_amdgcn_mfma_f32_32x32x16_bf16(a0h, bhB, acc01, 0,0,0); \
        acc10 = __builtin_amdgcn_mfma_f32_32x32x16_bf16(a1m, bhA, acc10, 0,0,0); \
        acc10 = __builtin_amdgcn_mfma_f32_32x32x16_bf16(a1h, bmA, acc10, 0,0,0); \
        acc10 = __builtin_amdgcn_mfma_f32_32x32x16_bf16(a1h, bhA, acc10, 0,0,0); \
        acc11 = __builtin_amdgcn_mfma_f32_32x32x16_bf16(a1m, bhB, acc11, 0,0,0); \
        acc11 = __builtin_amdgcn_mfma_f32_32x32x16_bf16(a1h, bmB, acc11, 0,0,0); \
        acc11 = __builtin_amdgcn_mfma_f32_32x32x16_bf16(a1h, bhB, acc11, 0,0,0); \
    }                                                                         \
} while (0)

    // prologue: W(0) first, then x(0), x(1)  -> outstanding [W0(8), x0(4), x1(4)]
    WSTAGE(0);
    XSTAGE(0);
    XSTAGE(1);
    for (int i = 0; i < nsteps; i++) {
        // steady state: drain oldest 12 (x(i) [+W(i/2) on even steps]), keep 4
        if (i + 1 < nsteps) asm volatile("s_waitcnt vmcnt(4)" ::: "memory");
        else                asm volatile("s_waitcnt vmcnt(0)" ::: "memory");
        __builtin_amdgcn_s_barrier();
        __builtin_amdgcn_sched_barrier(0);
        COMPUTE(i);
        __builtin_amdgcn_s_barrier();              // all waves done with x-buf & (odd) W
        __builtin_amdgcn_sched_barrier(0);
        if (i & 1) {                               // W BEFORE x: keeps oldest-4 exact
            const int w = (i + 1) >> 1;
            if (w < (nsteps >> 1)) WSTAGE(w);
        }
        if (i + 2 < nsteps) XSTAGE(i + 2);
    }
#undef XSTAGE
#undef WSTAGE
#undef CVT8
#undef COMPUTE

    // ---- store partials (t >= 100 discarded)
    const int rbase = 4 * h5;
    float* Pb = P + (size_t)s * T_STEPS * HTOT;
    const int hA = ht * 128 + wh + l31;
    const int hB = hA + 32;
#pragma unroll
    for (int reg = 0; reg < 16; reg++) {
        const int row = (reg & 3) + rbase + 8 * (reg >> 2);
        const int t0  = wt + row;
        const int t1  = wt + 32 + row;
        if (t0 < T_STEPS) {
            Pb[(size_t)t0 * HTOT + hA] = acc00[reg];
            Pb[(size_t)t0 * HTOT + hB] = acc01[reg];
        }
        if (t1 < T_STEPS) {
            Pb[(size_t)t1 * HTOT + hA] = acc10[reg];
            Pb[(size_t)t1 * HTOT + hB] = acc11[reg];
        }
    }
}

// reduce partials + bias -> cur1[t][h]   (float4 per thread, coalesced)
__global__ __launch_bounds__(256) void k_reduce(
    const float* __restrict__ P,
    const float* __restrict__ ab1, const float* __restrict__ cb1,
    float* __restrict__ cur1, int NS)
{
    int g4 = blockIdx.x * 256 + threadIdx.x;
    int g  = g4 * 4;
    int h0 = g & (HTOT - 1);
    float4 sum;
    sum.x = (h0 + 0 < HID) ? ab1[h0 + 0] : cb1[h0 + 0 - HID];
    sum.y = (h0 + 1 < HID) ? ab1[h0 + 1] : cb1[h0 + 1 - HID];
    sum.z = (h0 + 2 < HID) ? ab1[h0 + 2] : cb1[h0 + 2 - HID];
    sum.w = (h0 + 3 < HID) ? ab1[h0 + 3] : cb1[h0 + 3 - HID];
    for (int ss = 0; ss < NS; ss++) {
        float4 v = *(const float4*)(P + (size_t)ss * T_STEPS * HTOT + g);
        sum.x += v.x; sum.y += v.y; sum.z += v.z; sum.w += v.w;
    }
    *(float4*)(cur1 + g) = sum;
}

// LIF1: 8 blocks x 64 threads, thread = neuron, 10-deep current prefetch.
__global__ __launch_bounds__(64) void k_lif1(
    const float* __restrict__ cur1,
    unsigned long long* __restrict__ bitsws,
    float* __restrict__ wsa)
{
    const int b    = blockIdx.x;
    const int lane = threadIdx.x;
    const int n    = b * 64 + lane;

    float mem = 0.f;
    for (int tb = 0; tb < T_STEPS; tb += 10) {
        float c[10];
#pragma unroll
        for (int i = 0; i < 10; i++) c[i] = cur1[(size_t)(tb + i) * HTOT + n];
#pragma unroll
        for (int i = 0; i < 10; i++) {
            float reset = (mem > THRESH) ? THRESH : 0.f;
            mem = BETA * mem + c[i] - reset;
            unsigned long long m = __ballot(mem > THRESH);
            if (lane == 0) bitsws[(size_t)(tb + i) * 8 + b] = m;
        }
    }
    if (b == 0 && lane == 0) { wsa[0] = 0.f; wsa[1] = 0.f; }
}

// GEMM2 + LIF2: block per output neuron j (0..19 actor, 20 critic).
__global__ __launch_bounds__(128) void k_gemm2(
    const unsigned long long* __restrict__ bitsws,
    const float* __restrict__ aW2, const float* __restrict__ ab2,
    const float* __restrict__ cW2, const float* __restrict__ cb2,
    float* __restrict__ wsa, float* __restrict__ out)
{
    const int j   = blockIdx.x;
    const int tid = threadIdx.x;

    __shared__ float W[256];
    __shared__ float c2[T_STEPS];

    const float* Wsrc = (j < 20) ? (aW2 + j * 256) : cW2;
    for (int i = tid; i < 256; i += 128) W[i] = Wsrc[i];
    const float bias  = (j < 20) ? ab2[j] : cb2[0];
    const int   wbase = (j < 20) ? 0 : 4;
    __syncthreads();

    const int t = tid;
    if (t < T_STEPS) {
        unsigned long long m0 = bitsws[(size_t)t * 8 + wbase + 0];
        unsigned long long m1 = bitsws[(size_t)t * 8 + wbase + 1];
        unsigned long long m2 = bitsws[(size_t)t * 8 + wbase + 2];
        unsigned long long m3 = bitsws[(size_t)t * 8 + wbase + 3];
        float acc = bias;
#pragma unroll
        for (int bitp = 0; bitp < 64; bitp++) {
            acc += ((m0 >> bitp) & 1ULL) ? W[bitp]       : 0.f;
            acc += ((m1 >> bitp) & 1ULL) ? W[64 + bitp]  : 0.f;
            acc += ((m2 >> bitp) & 1ULL) ? W[128 + bitp] : 0.f;
            acc += ((m3 >> bitp) & 1ULL) ? W[192 + bitp] : 0.f;
        }
        c2[t] = acc;
    }
    __syncthreads();

    if (tid == 0) {
        float mem = 0.f, spk = 0.f;
        for (int tt = 0; tt < T_STEPS; tt++) {
            float reset = (mem > THRESH) ? THRESH : 0.f;
            mem = BETA * mem + c2[tt] - reset;
            spk += (mem > THRESH) ? 1.f : 0.f;
        }
        if (j < 10)       atomicAdd(&wsa[0], spk);   // exact: integer-valued floats
        else if (j < 20)  atomicAdd(&wsa[1], spk);
        else              out[2] = mem;
    }
}

__global__ __launch_bounds__(64) void k_final(
    const float* __restrict__ wsa, float* __restrict__ out)
{
    if (threadIdx.x == 0) {
        float a0 = wsa[0], a1 = wsa[1];
        float mx = fmaxf(a0, a1);
        float e0 = expf(a0 - mx), e1 = expf(a1 - mx);
        float inv = 1.f / (e0 + e1);
        out[0] = e0 * inv;
        out[1] = e1 * inv;
    }
}

extern "C" void kernel_launch(void* const* d_in, const int* in_sizes, int n_in,
                              void* d_out, int out_size, void* d_ws, size_t ws_size,
                              hipStream_t stream) {
    const float* x   = (const float*)d_in[0];
    const float* aW1 = (const float*)d_in[1];
    const float* ab1 = (const float*)d_in[2];
    const float* aW2 = (const float*)d_in[3];
    const float* ab2 = (const float*)d_in[4];
    const float* cW1 = (const float*)d_in[5];
    const float* cb1 = (const float*)d_in[6];
    const float* cW2 = (const float*)d_in[7];
    const float* cb2 = (const float*)d_in[8];
    float* out = (float*)d_out;

    const int NS = 128;                                    // fixed (swizzle assumes 128)
    const int nsteps = (D_IN / NS) / 32;                   // 16 (even)

    float* P    = (float*)d_ws;                            // [128][100][512]
    float* cur1 = P + (size_t)NS * T_STEPS * HTOT;         // [100][512]
    unsigned long long* bitsws =
        (unsigned long long*)(cur1 + T_STEPS * HTOT);      // [100][8]
    float* wsa = (float*)(bitsws + T_STEPS * 8);           // [2]

    k_gemm1 <<<512, 256, 0, stream>>>(aW1, cW1, x, P, nsteps);
    k_reduce<<<(T_STEPS * HTOT / 4) / 256, 256, 0, stream>>>(P, ab1, cb1, cur1, NS);
    k_lif1  <<<8, 64, 0, stream>>>(cur1, bitsws, wsa);
    k_gemm2 <<<21, 128, 0, stream>>>(bitsws, aW2, ab2, cW2, cb2, wsa, out);
    k_final <<<1, 64, 0, stream>>>(wsa, out);
}

// Round 15
// 87.986 us; speedup vs baseline: 1.1006x; 1.1006x over previous
//
#include <hip/hip_runtime.h>
#include <hip/hip_bf16.h>

#define T_STEPS 100
#define D_IN    65536
#define HID     256
#define HTOT    512
#define BETA    0.95f
#define THRESH  1.0f

typedef __bf16 bf16x8 __attribute__((ext_vector_type(8)));
typedef float  f32x16 __attribute__((ext_vector_type(16)));

__device__ __forceinline__ void gload_lds16(const void* g, void* l) {
    __builtin_amdgcn_global_load_lds(
        (const __attribute__((address_space(1))) void*)g,
        (__attribute__((address_space(3))) void*)l, 16, 0, 0);
}

// ---- GEMM1 (identical to R13's measured-best fused config).
// x + W staged fp32 via global_load_lds, converted to bf16 hi/mid in-COMPUTE.
// 2-buffer pipeline, 64 KB LDS -> 2 blocks/CU, counted vmcnt(8).
// Per 32-k step-buffer (32 KB): [0,16K) x fp32 [128 rows][8 swz granules],
// [16K,32K) W fp32 (same layout). Pad rows clamped to row 99 (garbage
// discarded at store). 3-product bf16 hi/mid MFMA.
// Block = 256 thr = 4 waves, wave owns 64t x 64h quadrant (2x2 accs).
// XCD-locality flat-grid swizzle (same-split h-tiles share an XCD's L2).
__global__ __launch_bounds__(256, 2) void k_gemm1(
    const float* __restrict__ aW1,   // [256][65536]
    const float* __restrict__ cW1,   // [256][65536]
    const float* __restrict__ x,     // [100][65536]
    float* __restrict__ P,           // [NS][100][512]
    int nsteps)                      // 32-k steps per split (16 at NS=128)
{
    // bijective swizzle: d -> xcd = d%8, slot = d/8, s = xcd*16+(slot&15), ht = slot>>4
    const int d    = blockIdx.x;
    const int xcd  = d & 7;
    const int sl   = d >> 3;
    const int s    = xcd * 16 + (sl & 15);
    const int ht   = sl >> 4;

    const int tid  = threadIdx.x;
    const int lane = tid & 63;
    const int l31  = lane & 31;
    const int h5   = lane >> 5;
    const int wv   = tid >> 6;           // 0..3
    const int wt   = (wv & 1) * 64;      // wave t-offset
    const int wh   = (wv >> 1) * 64;     // wave h-offset (64-wide quadrant)

    __shared__ __align__(16) char smem[2][32768];   // 64 KB

    const float* Wbase = (ht < 2) ? (aW1 + (size_t)ht * 128 * D_IN)
                                  : (cW1 + (size_t)(ht - 2) * 128 * D_IN);

    // staging: 8 gload_lds per thread per step (1024 x + 1024 W granules).
    // granule idx = o*256+tid -> (row = idx>>3, g = idx&7); LDS dest linear,
    // source column pre-swizzled (g ^ (row&7)) so swizzled LDS reads pair up.
    const float* xsrc[4];
    const float* wsrc[4];
#pragma unroll
    for (int o = 0; o < 4; o++) {
        const int idx = o * 256 + tid;
        const int row = idx >> 3, g = idx & 7;
        const int xrow = (row < T_STEPS) ? row : (T_STEPS - 1);  // clamp: pad rows discarded at store
        xsrc[o] = x     + (size_t)xrow * D_IN + (g ^ (row & 7)) * 4;
        wsrc[o] = Wbase + (size_t)row  * D_IN + (g ^ (row & 7)) * 4;
    }
    const int gk0 = s * nsteps;

    f32x16 acc00, acc01, acc10, acc11;
#pragma unroll
    for (int i = 0; i < 16; i++) {
        acc00[i] = 0.f; acc01[i] = 0.f; acc10[i] = 0.f; acc11[i] = 0.f;
    }

#define STAGE(i) do {                                                         \
    char* b_ = smem[(i) & 1];                                                 \
    const int kc_ = (gk0 + (i)) * 32;                                         \
    _Pragma("unroll")                                                         \
    for (int o = 0; o < 4; o++) {                                             \
        const int g_ = o * 256 + tid;                                         \
        gload_lds16(xsrc[o] + kc_, b_ + g_ * 16);                             \
    }                                                                         \
    _Pragma("unroll")                                                         \
    for (int o = 0; o < 4; o++) {                                             \
        const int g_ = o * 256 + tid;                                         \
        gload_lds16(wsrc[o] + kc_, b_ + 16384 + g_ * 16);                     \
    }                                                                         \
} while (0)

#define CVT8(dsth, dstm, va, vb) do {                                         \
    float f_[8] = {va.x, va.y, va.z, va.w, vb.x, vb.y, vb.z, vb.w};           \
    _Pragma("unroll")                                                         \
    for (int e = 0; e < 8; e++) {                                             \
        __bf16 h = (__bf16)f_[e];                                             \
        dsth[e] = h; dstm[e] = (__bf16)(f_[e] - (float)h);                    \
    }                                                                         \
} while (0)

#define COMPUTE(i) do {                                                       \
    const char* b_ = smem[(i) & 1];                                           \
    _Pragma("unroll")                                                         \
    for (int s16 = 0; s16 < 2; s16++) {                                       \
        const int slot_ = s16 * 2 + h5;                                       \
        const int gb    = slot_ * 2;                                          \
        /* A fragments: x fp32 rows r0, r1, granules gb/gb+1 (swizzled) */    \
        const int r0 = wt + l31, r1 = r0 + 32;                                \
        const char* xr0_ = b_ + r0 * 128;                                     \
        const char* xr1_ = b_ + r1 * 128;                                     \
        float4 xa0 = *(const float4*)(xr0_ + ((gb ^ (r0 & 7)) * 16));         \
        float4 xb0 = *(const float4*)(xr0_ + (((gb + 1) ^ (r0 & 7)) * 16));   \
        float4 xa1 = *(const float4*)(xr1_ + ((gb ^ (r1 & 7)) * 16));         \
        float4 xb1 = *(const float4*)(xr1_ + (((gb + 1) ^ (r1 & 7)) * 16));   \
        bf16x8 a0h, a0m, a1h, a1m;                                            \
        CVT8(a0h, a0m, xa0, xb0);                                             \
        CVT8(a1h, a1m, xa1, xb1);                                             \
        /* W fragments: two 32-row h-sets of the 64h quadrant */              \
        const int hrA = wh + l31, hrB = hrA + 32;                             \
        const char* wrA_ = b_ + 16384 + hrA * 128;                            \
        const char* wrB_ = b_ + 16384 + hrB * 128;                            \
        float4 waA = *(const float4*)(wrA_ + ((gb ^ (hrA & 7)) * 16));        \
        float4 wbA = *(const float4*)(wrA_ + (((gb + 1) ^ (hrA & 7)) * 16));  \
        float4 waB = *(const float4*)(wrB_ + ((gb ^ (hrB & 7)) * 16));        \
        float4 wbB = *(const float4*)(wrB_ + (((gb + 1) ^ (hrB & 7)) * 16));  \
        bf16x8 bhA, bmA, bhB, bmB;                                            \
        CVT8(bhA, bmA, waA, wbA);                                             \
        CVT8(bhB, bmB, waB, wbB);                                             \
        acc00 = __builtin_amdgcn_mfma_f32_32x32x16_bf16(a0m, bhA, acc00, 0,0,0); \
        acc00 = __builtin_amdgcn_mfma_f32_32x32x16_bf16(a0h, bmA, acc00, 0,0,0); \
        acc00 = __builtin_amdgcn_mfma_f32_32x32x16_bf16(a0h, bhA, acc00, 0,0,0); \
        acc01 = __builtin_amdgcn_mfma_f32_32x32x16_bf16(a0m, bhB, acc01, 0,0,0); \
        acc01 = __builtin_amdgcn_mfma_f32_32x32x16_bf16(a0h, bmB, acc01, 0,0,0); \
        acc01 = __builtin_amdgcn_mfma_f32_32x32x16_bf16(a0h, bhB, acc01, 0,0,0); \
        acc10 = __builtin_amdgcn_mfma_f32_32x32x16_bf16(a1m, bhA, acc10, 0,0,0); \
        acc10 = __builtin_amdgcn_mfma_f32_32x32x16_bf16(a1h, bmA, acc10, 0,0,0); \
        acc10 = __builtin_amdgcn_mfma_f32_32x32x16_bf16(a1h, bhA, acc10, 0,0,0); \
        acc11 = __builtin_amdgcn_mfma_f32_32x32x16_bf16(a1m, bhB, acc11, 0,0,0); \
        acc11 = __builtin_amdgcn_mfma_f32_32x32x16_bf16(a1h, bmB, acc11, 0,0,0); \
        acc11 = __builtin_amdgcn_mfma_f32_32x32x16_bf16(a1h, bhB, acc11, 0,0,0); \
    }                                                                         \
} while (0)

    STAGE(0);
    STAGE(1);
    for (int i = 0; i < nsteps; i++) {
        if (i + 1 < nsteps) asm volatile("s_waitcnt vmcnt(8)" ::: "memory");
        else                asm volatile("s_waitcnt vmcnt(0)" ::: "memory");
        __builtin_amdgcn_s_barrier();              // buf[i&1] staged for all
        __builtin_amdgcn_sched_barrier(0);
        COMPUTE(i);
        __builtin_amdgcn_s_barrier();              // all waves done with buf[i&1]
        __builtin_amdgcn_sched_barrier(0);
        if (i + 2 < nsteps) STAGE(i + 2);          // rides the next step
    }
#undef STAGE
#undef CVT8
#undef COMPUTE

    // ---- store partials (t >= 100 discarded -> pad-row garbage never escapes)
    const int rbase = 4 * h5;
    float* Pb = P + (size_t)s * T_STEPS * HTOT;
    const int hA = ht * 128 + wh + l31;
    const int hB = hA + 32;
#pragma unroll
    for (int reg = 0; reg < 16; reg++) {
        const int row = (reg & 3) + rbase + 8 * (reg >> 2);
        const int t0  = wt + row;
        const int t1  = wt + 32 + row;
        if (t0 < T_STEPS) {
            Pb[(size_t)t0 * HTOT + hA] = acc00[reg];
            Pb[(size_t)t0 * HTOT + hB] = acc01[reg];
        }
        if (t1 < T_STEPS) {
            Pb[(size_t)t1 * HTOT + hA] = acc10[reg];
            Pb[(size_t)t1 * HTOT + hB] = acc11[reg];
        }
    }
}

// reduce partials + bias -> cur1[t][h]; also zeroes the action accumulators
// (runs strictly before k_gemm2's atomics in stream order).
__global__ __launch_bounds__(256) void k_reduce(
    const float* __restrict__ P,
    const float* __restrict__ ab1, const float* __restrict__ cb1,
    float* __restrict__ cur1, float* __restrict__ wsa, int NS)
{
    if (blockIdx.x == 0 && threadIdx.x == 0) { wsa[0] = 0.f; wsa[1] = 0.f; }
    int g4 = blockIdx.x * 256 + threadIdx.x;
    int g  = g4 * 4;
    int h0 = g & (HTOT - 1);
    float4 sum;
    sum.x = (h0 + 0 < HID) ? ab1[h0 + 0] : cb1[h0 + 0 - HID];
    sum.y = (h0 + 1 < HID) ? ab1[h0 + 1] : cb1[h0 + 1 - HID];
    sum.z = (h0 + 2 < HID) ? ab1[h0 + 2] : cb1[h0 + 2 - HID];
    sum.w = (h0 + 3 < HID) ? ab1[h0 + 3] : cb1[h0 + 3 - HID];
    for (int ss = 0; ss < NS; ss++) {
        float4 v = *(const float4*)(P + (size_t)ss * T_STEPS * HTOT + g);
        sum.x += v.x; sum.y += v.y; sum.z += v.z; sum.w += v.w;
    }
    *(float4*)(cur1 + g) = sum;
}

// Merged LIF1 + GEMM2 + LIF2: block per output neuron j (0..19 actor,
// 20 critic), 256 threads. Each block recomputes LIF1 for its 256 source
// neurons in-block (10-deep prefetch), ballots spikes into LDS, then does
// the bitmask GEMM2 and the per-j LIF2. No bitsws round-trip, one launch.
__global__ __launch_bounds__(256) void k_gemm2(
    const float* __restrict__ cur1,  // [100][512]
    const float* __restrict__ aW2, const float* __restrict__ ab2,
    const float* __restrict__ cW2, const float* __restrict__ cb2,
    float* __restrict__ wsa, float* __restrict__ out)
{
    const int j   = blockIdx.x;      // 0..20
    const int tid = threadIdx.x;

    __shared__ float W[256];
    __shared__ unsigned long long bitsL[T_STEPS][4];
    __shared__ float c2[T_STEPS];

    const float* Wsrc = (j < 20) ? (aW2 + j * 256) : cW2;
    W[tid] = Wsrc[tid];
    const int base = (j < 20) ? 0 : 256;   // actor: neurons 0..255, critic: 256..511
    const int w    = tid >> 6;

    // LIF1 for this block's 256 source neurons (thread = neuron)
    {
        float mem = 0.f;
        for (int tb = 0; tb < T_STEPS; tb += 10) {
            float c[10];
#pragma unroll
            for (int i = 0; i < 10; i++)
                c[i] = cur1[(size_t)(tb + i) * HTOT + base + tid];
#pragma unroll
            for (int i = 0; i < 10; i++) {
                float reset = (mem > THRESH) ? THRESH : 0.f;
                mem = BETA * mem + c[i] - reset;
                unsigned long long m = __ballot(mem > THRESH);
                if ((tid & 63) == 0) bitsL[tb + i][w] = m;
            }
        }
    }
    __syncthreads();

    // GEMM2: thread = timestep; W reads are LDS broadcasts
    if (tid < T_STEPS) {
        unsigned long long m0 = bitsL[tid][0];
        unsigned long long m1 = bitsL[tid][1];
        unsigned long long m2 = bitsL[tid][2];
        unsigned long long m3 = bitsL[tid][3];
        float acc = (j < 20) ? ab2[j] : cb2[0];
#pragma unroll
        for (int b = 0; b < 64; b++) {
            acc += ((m0 >> b) & 1ULL) ? W[b]       : 0.f;
            acc += ((m1 >> b) & 1ULL) ? W[64 + b]  : 0.f;
            acc += ((m2 >> b) & 1ULL) ? W[128 + b] : 0.f;
            acc += ((m3 >> b) & 1ULL) ? W[192 + b] : 0.f;
        }
        c2[tid] = acc;
    }
    __syncthreads();

    // LIF2
    if (tid == 0) {
        float mem = 0.f, spk = 0.f;
        for (int t = 0; t < T_STEPS; t++) {
            float reset = (mem > THRESH) ? THRESH : 0.f;
            mem = BETA * mem + c2[t] - reset;
            spk += (mem > THRESH) ? 1.f : 0.f;
        }
        if (j < 10)       atomicAdd(&wsa[0], spk);   // exact: integer-valued floats
        else if (j < 20)  atomicAdd(&wsa[1], spk);
        else              out[2] = mem;              // critic final membrane
    }
}

__global__ __launch_bounds__(64) void k_final(
    const float* __restrict__ wsa, float* __restrict__ out)
{
    if (threadIdx.x == 0) {
        float a0 = wsa[0], a1 = wsa[1];
        float mx = fmaxf(a0, a1);
        float e0 = expf(a0 - mx), e1 = expf(a1 - mx);
        float inv = 1.f / (e0 + e1);
        out[0] = e0 * inv;
        out[1] = e1 * inv;
    }
}

extern "C" void kernel_launch(void* const* d_in, const int* in_sizes, int n_in,
                              void* d_out, int out_size, void* d_ws, size_t ws_size,
                              hipStream_t stream) {
    const float* x   = (const float*)d_in[0];
    const float* aW1 = (const float*)d_in[1];
    const float* ab1 = (const float*)d_in[2];
    const float* aW2 = (const float*)d_in[3];
    const float* ab2 = (const float*)d_in[4];
    const float* cW1 = (const float*)d_in[5];
    const float* cb1 = (const float*)d_in[6];
    const float* cW2 = (const float*)d_in[7];
    const float* cb2 = (const float*)d_in[8];
    float* out = (float*)d_out;

    const int NS = 128;                                    // fixed (swizzle assumes 128)
    const int nsteps = (D_IN / NS) / 32;                   // 16

    float* P    = (float*)d_ws;                            // [128][100][512]
    float* cur1 = P + (size_t)NS * T_STEPS * HTOT;         // [100][512]
    float* wsa  = cur1 + T_STEPS * HTOT;                   // [2]

    k_gemm1 <<<512, 256, 0, stream>>>(aW1, cW1, x, P, nsteps);
    k_reduce<<<(T_STEPS * HTOT / 4) / 256, 256, 0, stream>>>(P, ab1, cb1, cur1, wsa, NS);
    k_gemm2 <<<21, 256, 0, stream>>>(cur1, aW2, ab2, cW2, cb2, wsa, out);
    k_final <<<1, 64, 0, stream>>>(wsa, out);
}

// Round 16
// 87.964 us; speedup vs baseline: 1.1009x; 1.0003x over previous
//
#include <hip/hip_runtime.h>
#include <hip/hip_bf16.h>

#define T_STEPS 100
#define D_IN    65536
#define HID     256
#define HTOT    512
#define BETA    0.95f
#define THRESH  1.0f

typedef __bf16 bf16x8 __attribute__((ext_vector_type(8)));
typedef float  f32x16 __attribute__((ext_vector_type(16)));

__device__ __forceinline__ void gload_lds16(const void* g, void* l) {
    __builtin_amdgcn_global_load_lds(
        (const __attribute__((address_space(1))) void*)g,
        (__attribute__((address_space(3))) void*)l, 16, 0, 0);
}

// ---- GEMM1 (byte-identical to R15's measured-best config).
// x + W staged fp32 via global_load_lds, converted to bf16 hi/mid in-COMPUTE.
// 2-buffer pipeline, 64 KB LDS -> 2 blocks/CU, counted vmcnt(8).
// Per 32-k step-buffer (32 KB): [0,16K) x fp32 [128 rows][8 swz granules],
// [16K,32K) W fp32 (same layout). Pad rows clamped to row 99 (garbage
// discarded at store). 3-product bf16 hi/mid MFMA.
// Block = 256 thr = 4 waves, wave owns 64t x 64h quadrant (2x2 accs).
// XCD-locality flat-grid swizzle (same-split h-tiles share an XCD's L2).
__global__ __launch_bounds__(256, 2) void k_gemm1(
    const float* __restrict__ aW1,   // [256][65536]
    const float* __restrict__ cW1,   // [256][65536]
    const float* __restrict__ x,     // [100][65536]
    float* __restrict__ P,           // [NS][100][512]
    int nsteps)                      // 32-k steps per split (16 at NS=128)
{
    // bijective swizzle: d -> xcd = d%8, slot = d/8, s = xcd*16+(slot&15), ht = slot>>4
    const int d    = blockIdx.x;
    const int xcd  = d & 7;
    const int sl   = d >> 3;
    const int s    = xcd * 16 + (sl & 15);
    const int ht   = sl >> 4;

    const int tid  = threadIdx.x;
    const int lane = tid & 63;
    const int l31  = lane & 31;
    const int h5   = lane >> 5;
    const int wv   = tid >> 6;           // 0..3
    const int wt   = (wv & 1) * 64;      // wave t-offset
    const int wh   = (wv >> 1) * 64;     // wave h-offset (64-wide quadrant)

    __shared__ __align__(16) char smem[2][32768];   // 64 KB

    const float* Wbase = (ht < 2) ? (aW1 + (size_t)ht * 128 * D_IN)
                                  : (cW1 + (size_t)(ht - 2) * 128 * D_IN);

    const float* xsrc[4];
    const float* wsrc[4];
#pragma unroll
    for (int o = 0; o < 4; o++) {
        const int idx = o * 256 + tid;
        const int row = idx >> 3, g = idx & 7;
        const int xrow = (row < T_STEPS) ? row : (T_STEPS - 1);  // clamp: pad rows discarded at store
        xsrc[o] = x     + (size_t)xrow * D_IN + (g ^ (row & 7)) * 4;
        wsrc[o] = Wbase + (size_t)row  * D_IN + (g ^ (row & 7)) * 4;
    }
    const int gk0 = s * nsteps;

    f32x16 acc00, acc01, acc10, acc11;
#pragma unroll
    for (int i = 0; i < 16; i++) {
        acc00[i] = 0.f; acc01[i] = 0.f; acc10[i] = 0.f; acc11[i] = 0.f;
    }

#define STAGE(i) do {                                                         \
    char* b_ = smem[(i) & 1];                                                 \
    const int kc_ = (gk0 + (i)) * 32;                                         \
    _Pragma("unroll")                                                         \
    for (int o = 0; o < 4; o++) {                                             \
        const int g_ = o * 256 + tid;                                         \
        gload_lds16(xsrc[o] + kc_, b_ + g_ * 16);                             \
    }                                                                         \
    _Pragma("unroll")                                                         \
    for (int o = 0; o < 4; o++) {                                             \
        const int g_ = o * 256 + tid;                                         \
        gload_lds16(wsrc[o] + kc_, b_ + 16384 + g_ * 16);                     \
    }                                                                         \
} while (0)

#define CVT8(dsth, dstm, va, vb) do {                                         \
    float f_[8] = {va.x, va.y, va.z, va.w, vb.x, vb.y, vb.z, vb.w};           \
    _Pragma("unroll")                                                         \
    for (int e = 0; e < 8; e++) {                                             \
        __bf16 h = (__bf16)f_[e];                                             \
        dsth[e] = h; dstm[e] = (__bf16)(f_[e] - (float)h);                    \
    }                                                                         \
} while (0)

#define COMPUTE(i) do {                                                       \
    const char* b_ = smem[(i) & 1];                                           \
    _Pragma("unroll")                                                         \
    for (int s16 = 0; s16 < 2; s16++) {                                       \
        const int slot_ = s16 * 2 + h5;                                       \
        const int gb    = slot_ * 2;                                          \
        const int r0 = wt + l31, r1 = r0 + 32;                                \
        const char* xr0_ = b_ + r0 * 128;                                     \
        const char* xr1_ = b_ + r1 * 128;                                     \
        float4 xa0 = *(const float4*)(xr0_ + ((gb ^ (r0 & 7)) * 16));         \
        float4 xb0 = *(const float4*)(xr0_ + (((gb + 1) ^ (r0 & 7)) * 16));   \
        float4 xa1 = *(const float4*)(xr1_ + ((gb ^ (r1 & 7)) * 16));         \
        float4 xb1 = *(const float4*)(xr1_ + (((gb + 1) ^ (r1 & 7)) * 16));   \
        bf16x8 a0h, a0m, a1h, a1m;                                            \
        CVT8(a0h, a0m, xa0, xb0);                                             \
        CVT8(a1h, a1m, xa1, xb1);                                             \
        const int hrA = wh + l31, hrB = hrA + 32;                             \
        const char* wrA_ = b_ + 16384 + hrA * 128;                            \
        const char* wrB_ = b_ + 16384 + hrB * 128;                            \
        float4 waA = *(const float4*)(wrA_ + ((gb ^ (hrA & 7)) * 16));        \
        float4 wbA = *(const float4*)(wrA_ + (((gb + 1) ^ (hrA & 7)) * 16));  \
        float4 waB = *(const float4*)(wrB_ + ((gb ^ (hrB & 7)) * 16));        \
        float4 wbB = *(const float4*)(wrB_ + (((gb + 1) ^ (hrB & 7)) * 16));  \
        bf16x8 bhA, bmA, bhB, bmB;                                            \
        CVT8(bhA, bmA, waA, wbA);                                             \
        CVT8(bhB, bmB, waB, wbB);                                             \
        acc00 = __builtin_amdgcn_mfma_f32_32x32x16_bf16(a0m, bhA, acc00, 0,0,0); \
        acc00 = __builtin_amdgcn_mfma_f32_32x32x16_bf16(a0h, bmA, acc00, 0,0,0); \
        acc00 = __builtin_amdgcn_mfma_f32_32x32x16_bf16(a0h, bhA, acc00, 0,0,0); \
        acc01 = __builtin_amdgcn_mfma_f32_32x32x16_bf16(a0m, bhB, acc01, 0,0,0); \
        acc01 = __builtin_amdgcn_mfma_f32_32x32x16_bf16(a0h, bmB, acc01, 0,0,0); \
        acc01 = __builtin_amdgcn_mfma_f32_32x32x16_bf16(a0h, bhB, acc01, 0,0,0); \
        acc10 = __builtin_amdgcn_mfma_f32_32x32x16_bf16(a1m, bhA, acc10, 0,0,0); \
        acc10 = __builtin_amdgcn_mfma_f32_32x32x16_bf16(a1h, bmA, acc10, 0,0,0); \
        acc10 = __builtin_amdgcn_mfma_f32_32x32x16_bf16(a1h, bhA, acc10, 0,0,0); \
        acc11 = __builtin_amdgcn_mfma_f32_32x32x16_bf16(a1m, bhB, acc11, 0,0,0); \
        acc11 = __builtin_amdgcn_mfma_f32_32x32x16_bf16(a1h, bmB, acc11, 0,0,0); \
        acc11 = __builtin_amdgcn_mfma_f32_32x32x16_bf16(a1h, bhB, acc11, 0,0,0); \
    }                                                                         \
} while (0)

    STAGE(0);
    STAGE(1);
    for (int i = 0; i < nsteps; i++) {
        if (i + 1 < nsteps) asm volatile("s_waitcnt vmcnt(8)" ::: "memory");
        else                asm volatile("s_waitcnt vmcnt(0)" ::: "memory");
        __builtin_amdgcn_s_barrier();              // buf[i&1] staged for all
        __builtin_amdgcn_sched_barrier(0);
        COMPUTE(i);
        __builtin_amdgcn_s_barrier();              // all waves done with buf[i&1]
        __builtin_amdgcn_sched_barrier(0);
        if (i + 2 < nsteps) STAGE(i + 2);          // rides the next step
    }
#undef STAGE
#undef CVT8
#undef COMPUTE

    // ---- store partials (t >= 100 discarded -> pad-row garbage never escapes)
    const int rbase = 4 * h5;
    float* Pb = P + (size_t)s * T_STEPS * HTOT;
    const int hA = ht * 128 + wh + l31;
    const int hB = hA + 32;
#pragma unroll
    for (int reg = 0; reg < 16; reg++) {
        const int row = (reg & 3) + rbase + 8 * (reg >> 2);
        const int t0  = wt + row;
        const int t1  = wt + 32 + row;
        if (t0 < T_STEPS) {
            Pb[(size_t)t0 * HTOT + hA] = acc00[reg];
            Pb[(size_t)t0 * HTOT + hB] = acc01[reg];
        }
        if (t1 < T_STEPS) {
            Pb[(size_t)t1 * HTOT + hA] = acc10[reg];
            Pb[(size_t)t1 * HTOT + hB] = acc11[reg];
        }
    }
}

// reduce partials + bias -> cur1[t][h] (float2/thread, 100 blocks for TLP);
// zeroes the action accumulators + completion counter (stream-before gemm2).
__global__ __launch_bounds__(256) void k_reduce(
    const float* __restrict__ P,
    const float* __restrict__ ab1, const float* __restrict__ cb1,
    float* __restrict__ cur1, float* __restrict__ wsa,
    unsigned* __restrict__ cnt, int NS)
{
    if (blockIdx.x == 0 && threadIdx.x == 0) {
        wsa[0] = 0.f; wsa[1] = 0.f; *cnt = 0u;
    }
    int g2 = blockIdx.x * 256 + threadIdx.x;   // 0..25599
    int g  = g2 * 2;
    int h0 = g & (HTOT - 1);
    float2 sum;
    sum.x = (h0 + 0 < HID) ? ab1[h0 + 0] : cb1[h0 + 0 - HID];
    sum.y = (h0 + 1 < HID) ? ab1[h0 + 1] : cb1[h0 + 1 - HID];
    for (int ss = 0; ss < NS; ss++) {
        float2 v = *(const float2*)(P + (size_t)ss * T_STEPS * HTOT + g);
        sum.x += v.x; sum.y += v.y;
    }
    *(float2*)(cur1 + g) = sum;
}

// Merged LIF1 + GEMM2 + LIF2 + (last-block) softmax.
// Block per output neuron j (0..19 actor, 20 critic), 256 threads.
// Each block recomputes LIF1 for its 256 source neurons (10-deep prefetch),
// ballots spikes into LDS, bitmask GEMM2, per-j LIF2, atomic action sums.
// The LAST block (completion counter) computes the softmax -> out[0..1].
__global__ __launch_bounds__(256) void k_gemm2(
    const float* __restrict__ cur1,  // [100][512]
    const float* __restrict__ aW2, const float* __restrict__ ab2,
    const float* __restrict__ cW2, const float* __restrict__ cb2,
    float* __restrict__ wsa, unsigned* __restrict__ cnt,
    float* __restrict__ out)
{
    const int j   = blockIdx.x;      // 0..20
    const int tid = threadIdx.x;

    __shared__ float W[256];
    __shared__ unsigned long long bitsL[T_STEPS][4];
    __shared__ float c2[T_STEPS];

    const float* Wsrc = (j < 20) ? (aW2 + j * 256) : cW2;
    W[tid] = Wsrc[tid];
    const int base = (j < 20) ? 0 : 256;   // actor: neurons 0..255, critic: 256..511
    const int w    = tid >> 6;

    // LIF1 for this block's 256 source neurons (thread = neuron)
    {
        float mem = 0.f;
        for (int tb = 0; tb < T_STEPS; tb += 10) {
            float c[10];
#pragma unroll
            for (int i = 0; i < 10; i++)
                c[i] = cur1[(size_t)(tb + i) * HTOT + base + tid];
#pragma unroll
            for (int i = 0; i < 10; i++) {
                float reset = (mem > THRESH) ? THRESH : 0.f;
                mem = BETA * mem + c[i] - reset;
                unsigned long long m = __ballot(mem > THRESH);
                if ((tid & 63) == 0) bitsL[tb + i][w] = m;
            }
        }
    }
    __syncthreads();

    // GEMM2: thread = timestep; W reads are LDS broadcasts
    if (tid < T_STEPS) {
        unsigned long long m0 = bitsL[tid][0];
        unsigned long long m1 = bitsL[tid][1];
        unsigned long long m2 = bitsL[tid][2];
        unsigned long long m3 = bitsL[tid][3];
        float acc = (j < 20) ? ab2[j] : cb2[0];
#pragma unroll
        for (int b = 0; b < 64; b++) {
            acc += ((m0 >> b) & 1ULL) ? W[b]       : 0.f;
            acc += ((m1 >> b) & 1ULL) ? W[64 + b]  : 0.f;
            acc += ((m2 >> b) & 1ULL) ? W[128 + b] : 0.f;
            acc += ((m3 >> b) & 1ULL) ? W[192 + b] : 0.f;
        }
        c2[tid] = acc;
    }
    __syncthreads();

    // LIF2 + action-sum atomics + last-block softmax
    if (tid == 0) {
        float mem = 0.f, spk = 0.f;
        for (int t = 0; t < T_STEPS; t++) {
            float reset = (mem > THRESH) ? THRESH : 0.f;
            mem = BETA * mem + c2[t] - reset;
            spk += (mem > THRESH) ? 1.f : 0.f;
        }
        if (j < 10)       atomicAdd(&wsa[0], spk);   // exact: integer-valued floats
        else if (j < 20)  atomicAdd(&wsa[1], spk);
        else              out[2] = mem;              // critic final membrane
        __threadfence();
        unsigned done = atomicAdd(cnt, 1u);
        if (done == 20u) {                           // last of 21 blocks
            // device-scope reads (atomic +0) — safe across non-coherent XCD L2s
            float a0 = atomicAdd(&wsa[0], 0.f);
            float a1 = atomicAdd(&wsa[1], 0.f);
            float mx = fmaxf(a0, a1);
            float e0 = expf(a0 - mx), e1 = expf(a1 - mx);
            float inv = 1.f / (e0 + e1);
            out[0] = e0 * inv;
            out[1] = e1 * inv;
        }
    }
}

extern "C" void kernel_launch(void* const* d_in, const int* in_sizes, int n_in,
                              void* d_out, int out_size, void* d_ws, size_t ws_size,
                              hipStream_t stream) {
    const float* x   = (const float*)d_in[0];
    const float* aW1 = (const float*)d_in[1];
    const float* ab1 = (const float*)d_in[2];
    const float* aW2 = (const float*)d_in[3];
    const float* ab2 = (const float*)d_in[4];
    const float* cW1 = (const float*)d_in[5];
    const float* cb1 = (const float*)d_in[6];
    const float* cW2 = (const float*)d_in[7];
    const float* cb2 = (const float*)d_in[8];
    float* out = (float*)d_out;

    const int NS = 128;                                    // fixed (swizzle assumes 128)
    const int nsteps = (D_IN / NS) / 32;                   // 16

    float* P    = (float*)d_ws;                            // [128][100][512]
    float* cur1 = P + (size_t)NS * T_STEPS * HTOT;         // [100][512]
    float* wsa  = cur1 + T_STEPS * HTOT;                   // [2]
    unsigned* cnt = (unsigned*)(wsa + 2);                  // [1]

    k_gemm1 <<<512, 256, 0, stream>>>(aW1, cW1, x, P, nsteps);
    k_reduce<<<(T_STEPS * HTOT / 2) / 256, 256, 0, stream>>>(P, ab1, cb1, cur1, wsa, cnt, NS);
    k_gemm2 <<<21, 256, 0, stream>>>(cur1, aW2, ab2, cW2, cb2, wsa, cnt, out);
}